// Round 11
// baseline (469.515 us; speedup 1.0000x reference)
//
#include <hip/hip_runtime.h>
#include <hip/hip_fp8.h>

#define BB 8
#define NN 4096
#define MM 4096
#define DD 128

typedef float f32x4 __attribute__((ext_vector_type(4)));
typedef long  long2v __attribute__((ext_vector_type(2)));

// ---------------------------------------------------------------------------
// Fragment-ordered fp8 layout (verified R7-R10, absmax 0): for 16-row group
// g, K-half h, the 1KB unit holds lane(quad,l15) -> 16B: row=l15 (in group),
// k=(2h+p)*32+quad*8+(0..7) at byte p*8+(k&7).
// ---------------------------------------------------------------------------

// Prep: one row per 32 lanes, float4/thread, HW packed fp8 convert
// (v_cvt_pk_fp8_f32 — 2 instrs per float4 vs ~80 for the emulated libcall),
// exact fp32 norms via shfl, scattered 4B fragment-ordered stores.
__global__ __launch_bounds__(256)
void prep_all(const float* __restrict__ x, const float* __restrict__ y,
              unsigned char* __restrict__ xq, unsigned char* __restrict__ yq,
              float* __restrict__ x2, float* __restrict__ y2,
              unsigned int* __restrict__ fwd, unsigned int* __restrict__ counter) {
    int gtid = blockIdx.x * blockDim.x + threadIdx.x;
    if (gtid < BB * MM) fwd[gtid] = 0x7f800000u;  // +inf bits
    if (gtid == 0) *counter = 0u;

    int row = gtid >> 5;
    int k4  = gtid & 31;
    const float* src;
    unsigned char* dst;
    float* sq;
    if (row < BB * NN) {
        src = x; dst = xq; sq = x2;
    } else {
        src = y; dst = yq; sq = y2; row -= BB * NN;
    }
    f32x4 v = ((const f32x4*)src)[(size_t)row * 32 + k4];
    float s = v.x * v.x + v.y * v.y + v.z * v.z + v.w * v.w;
    // bytes: [x][y][z][w] little-endian, same packing as before (verified)
    unsigned int p32 = (unsigned int)__builtin_amdgcn_cvt_pk_fp8_f32(v.x, v.y, 0, false);
    p32 = (unsigned int)__builtin_amdgcn_cvt_pk_fp8_f32(v.z, v.w, (int)p32, true);

    int k    = k4 << 2;
    int kk   = k >> 5;
    int h    = kk >> 1;
    int p    = kk & 1;
    int quad = (k >> 3) & 3;
    size_t dstoff = ((size_t)(row >> 4) * 2 + h) * 1024
                  + (size_t)(quad * 16 + (row & 15)) * 16 + p * 8 + (k & 7);
    *(unsigned int*)(dst + dstoff) = p32;

    #pragma unroll
    for (int m = 16; m; m >>= 1) s += __shfl_xor(s, m, 64);  // stays in 32-half
    if (k4 == 0) sq[row] = s;
}

// ---------------------------------------------------------------------------
// Main: wave tile 32n x 32m, block 128n x 32m (R9/R10 structure). Changes:
// (1) sched_barrier(0) after the b+1 prefetch so the compiler cannot sink
//     the loads to their use (keeps the register double-buffer LIVE; the
//     vmcnt wait for batch b then sits one full iteration behind issue).
// (2) finalize merged back in (last-block pattern) — kills the 3rd launch.
// ---------------------------------------------------------------------------
__global__ __launch_bounds__(256, 4)
void chamfer_main(const unsigned char* __restrict__ xq, const unsigned char* __restrict__ yq,
                  const float* __restrict__ x2, const float* __restrict__ y2,
                  unsigned int* __restrict__ fwd, float* __restrict__ bpart,
                  unsigned int* __restrict__ counter, float* __restrict__ out) {
    __shared__ float x2s[BB][128];          // 4 KB
    __shared__ float y2s[BB][32];           // 1 KB
    __shared__ unsigned int fbuf[BB][32];   // 1 KB
    __shared__ float red[4], redb[4];
    __shared__ int isLast;

    const int tid  = threadIdx.x;
    const int lane = tid & 63;
    const int wave = tid >> 6;
    const int quad = lane >> 4;
    const int l15  = lane & 15;

    // 4096 blocks; per-XCD m-stripe: xcd = id&7 -> mb = xcd*16 + (j>>5)
    const int id  = blockIdx.x;
    const int xcd = id & 7;
    const int j   = id >> 3;                 // 0..511
    const int nb  = j & 31;                  // 0..31 (128 n each)
    const int mb  = xcd * 16 + (j >> 5);     // 0..127 (32 m each)
    const int n0b = nb * 128;
    const int n0w = n0b + wave * 32;
    const int m0  = mb * 32;

    const size_t lane16 = (size_t)lane * 16;
    const unsigned char* xbase = xq + (size_t)(n0w >> 4) * 2048 + lane16;
    const unsigned char* ybase = yq + (size_t)(m0 >> 4) * 2048 + lane16;

    // stage norms + init fbuf (once), then the only pre-loop barrier
    for (int i = tid; i < BB * 128; i += 256)
        x2s[i >> 7][i & 127] = x2[(size_t)(i >> 7) * NN + n0b + (i & 127)];
    if (tid < BB * 32) {
        y2s[tid >> 5][tid & 31] = y2[(size_t)(tid >> 5) * MM + m0 + (tid & 31)];
        ((unsigned int*)fbuf)[tid] = 0x7f800000u;
    }
    __syncthreads();

    long2v fx[2][2][2], fy[2][2][2];  // [buf][group][half]
    auto loadb = [&](int b, int s) {
        const unsigned char* xb = xbase + ((size_t)b << 19);  // b*256 groups*2KB
        const unsigned char* yb = ybase + ((size_t)b << 19);
        #pragma unroll
        for (int g2 = 0; g2 < 2; ++g2)
            #pragma unroll
            for (int h = 0; h < 2; ++h) {
                fx[s][g2][h] = *(const long2v*)(xb + ((g2 * 2 + h) << 10));
                fy[s][g2][h] = *(const long2v*)(yb + ((g2 * 2 + h) << 10));
            }
    };
    loadb(0, 0);

    const float INF = __builtin_inff();
    f32x4 bmin[2][2];
    #pragma unroll
    for (int fi = 0; fi < 2; ++fi)
        #pragma unroll
        for (int fj = 0; fj < 2; ++fj)
            bmin[fi][fj] = (f32x4){INF, INF, INF, INF};

    #pragma unroll 2
    for (int b = 0; b < BB; ++b) {
        const int cur = b & 1;
        if (b < BB - 1) loadb(b + 1, cur ^ 1);  // the ONLY vmem in the loop
        // pin: prefetch loads may not sink below this point
        __builtin_amdgcn_sched_barrier(0);

        f32x4 acc[2][2];
        #pragma unroll
        for (int fi = 0; fi < 2; ++fi)
            #pragma unroll
            for (int fj = 0; fj < 2; ++fj)
                acc[fi][fj] = (f32x4){0.f, 0.f, 0.f, 0.f};

        #pragma unroll
        for (int h = 0; h < 2; ++h)
            #pragma unroll
            for (int p = 0; p < 2; ++p)
                #pragma unroll
                for (int fi = 0; fi < 2; ++fi)
                    #pragma unroll
                    for (int fj = 0; fj < 2; ++fj)
                        acc[fi][fj] = __builtin_amdgcn_mfma_f32_16x16x32_fp8_fp8(
                            fx[cur][fi][h][p], fy[cur][fj][h][p], acc[fi][fj], 0, 0, 0);

        // epilogue on SQUARED distances; norms from LDS; NO shfl, NO branch
        float y2v[2];
        y2v[0] = y2s[b][l15];
        y2v[1] = y2s[b][16 + l15];
        float fm[2] = {INF, INF};
        #pragma unroll
        for (int fi = 0; fi < 2; ++fi) {
            const f32x4 x2v = *(const f32x4*)&x2s[b][wave * 32 + fi * 16 + quad * 4];
            #pragma unroll
            for (int fj = 0; fj < 2; ++fj)
                #pragma unroll
                for (int e = 0; e < 4; ++e) {
                    float sqv = fmaf(-2.0f, acc[fi][fj][e], x2v[e] + y2v[fj]);
                    bmin[fi][fj][e] = fminf(bmin[fi][fj][e], sqv);
                    fm[fj]          = fminf(fm[fj], sqv);
                }
        }
        #pragma unroll
        for (int fj = 0; fj < 2; ++fj) {
            // 4 quads same address: no-return ds_min, pipelined, no chain
            atomicMin(&fbuf[b][fj * 16 + l15],
                      __float_as_uint(fmaxf(fm[fj], 0.0f)));
        }
    }
    __syncthreads();  // all waves' fbuf contributions visible

    // flush forward mins: 256 entries, one per thread
    {
        int b = tid >> 5, c = tid & 31;
        atomicMin(&fwd[(size_t)b * MM + m0 + c], fbuf[b][c]);
    }

    // backward: sqrt(clamp(min-over-b)), block-reduce, ONE plain store/block
    float s = 0.0f;
    #pragma unroll
    for (int fi = 0; fi < 2; ++fi)
        #pragma unroll
        for (int fj = 0; fj < 2; ++fj)
            #pragma unroll
            for (int e = 0; e < 4; ++e)
                s += sqrtf(fmaxf(bmin[fi][fj][e], 0.0f));
    #pragma unroll
    for (int off = 32; off; off >>= 1) s += __shfl_down(s, off, 64);
    if (lane == 0) red[wave] = s;
    __syncthreads();
    if (tid == 0) bpart[id] = red[0] + red[1] + red[2] + red[3];

    // merged finalize: last block reduces fwd (128 KB, L2-resident) + bpart
    __threadfence();
    __syncthreads();
    if (tid == 0) {
        unsigned int c = atomicAdd(counter, 1u);
        isLast = (c == (unsigned int)(gridDim.x - 1)) ? 1 : 0;
    }
    __syncthreads();
    if (isLast) {
        __threadfence();
        float sf = 0.0f, sb = 0.0f;
        const uint4* fw4 = (const uint4*)fwd;
        for (int i = tid; i < (BB * MM) / 4; i += 256) {
            uint4 u = fw4[i];
            sf += sqrtf(__uint_as_float(u.x)) + sqrtf(__uint_as_float(u.y)) +
                  sqrtf(__uint_as_float(u.z)) + sqrtf(__uint_as_float(u.w));
        }
        for (int i = tid; i < 4096; i += 256) sb += bpart[i];
        #pragma unroll
        for (int off = 32; off; off >>= 1) {
            sf += __shfl_down(sf, off, 64);
            sb += __shfl_down(sb, off, 64);
        }
        if (lane == 0) { red[wave] = sf; redb[wave] = sb; }
        __syncthreads();
        if (tid == 0) {
            float ftot = red[0] + red[1] + red[2] + red[3];
            float btot = redb[0] + redb[1] + redb[2] + redb[3];
            out[0] = ftot / (float)(BB * MM) + btot / ((float)NN * (float)MM);
        }
    }
}

extern "C" void kernel_launch(void* const* d_in, const int* in_sizes, int n_in,
                              void* d_out, int out_size, void* d_ws, size_t ws_size,
                              hipStream_t stream) {
    const float* x = (const float*)d_in[0];  // (B,N,D)
    const float* y = (const float*)d_in[1];  // (B,M,D)
    float* out = (float*)d_out;

    char* w = (char*)d_ws;
    unsigned char* xq = (unsigned char*)(w);               // 4 MB fp8 (frag order)
    unsigned char* yq = (unsigned char*)(w + 4194304);     // 4 MB fp8 (frag order)
    float*    x2 = (float*)(w + 8388608);                  // 128 KB
    float*    y2 = (float*)(w + 8519680);                  // 128 KB
    unsigned int* fwd = (unsigned int*)(w + 8650752);      // 128 KB
    float*    bpart = (float*)(w + 8781824);               // 16 KB
    unsigned int* counter = (unsigned int*)(w + 8798208);  // 4 B

    // 65536 rows, one per 32 lanes -> 2M threads
    prep_all<<<(2 * BB * NN * 32) / 256, 256, 0, stream>>>(x, y, xq, yq, x2, y2,
                                                           fwd, counter);
    chamfer_main<<<4096, 256, 0, stream>>>(xq, yq, x2, y2, fwd, bpart, counter, out);
}

// Round 12
// 465.201 us; speedup vs baseline: 1.0093x; 1.0093x over previous
//
#include <hip/hip_runtime.h>
#include <hip/hip_fp8.h>

#define BB 8
#define NN 4096
#define MM 4096
#define DD 128

typedef float f32x4 __attribute__((ext_vector_type(4)));
typedef long  long2v __attribute__((ext_vector_type(2)));

// ---------------------------------------------------------------------------
// Fragment-ordered fp8 layout (verified R7-R10, absmax 0): for 16-row group
// g, K-half h, the 1KB unit holds lane(quad,l15) -> 16B: row=l15 (in group),
// k=(2h+p)*32+quad*8+(0..7) at byte p*8+(k&7).
// ---------------------------------------------------------------------------

// Prep: one row per 32 lanes, float4/thread, HW packed fp8 convert
// (v_cvt_pk_fp8_f32 — 2 instrs per float4 vs ~80 for the emulated libcall),
// exact fp32 norms via shfl, scattered 4B fragment-ordered stores.
__global__ __launch_bounds__(256)
void prep_all(const float* __restrict__ x, const float* __restrict__ y,
              unsigned char* __restrict__ xq, unsigned char* __restrict__ yq,
              float* __restrict__ x2, float* __restrict__ y2,
              unsigned int* __restrict__ fwd, unsigned int* __restrict__ counter) {
    int gtid = blockIdx.x * blockDim.x + threadIdx.x;
    if (gtid < BB * MM) fwd[gtid] = 0x7f800000u;  // +inf bits
    if (gtid == 0) *counter = 0u;

    int row = gtid >> 5;
    int k4  = gtid & 31;
    const float* src;
    unsigned char* dst;
    float* sq;
    if (row < BB * NN) {
        src = x; dst = xq; sq = x2;
    } else {
        src = y; dst = yq; sq = y2; row -= BB * NN;
    }
    f32x4 v = ((const f32x4*)src)[(size_t)row * 32 + k4];
    float s = v.x * v.x + v.y * v.y + v.z * v.z + v.w * v.w;
    // bytes: [x][y][z][w] little-endian (verified vs emulated path, absmax 0)
    unsigned int p32 = (unsigned int)__builtin_amdgcn_cvt_pk_fp8_f32(v.x, v.y, 0, false);
    p32 = (unsigned int)__builtin_amdgcn_cvt_pk_fp8_f32(v.z, v.w, (int)p32, true);

    int k    = k4 << 2;
    int kk   = k >> 5;
    int h    = kk >> 1;
    int p    = kk & 1;
    int quad = (k >> 3) & 3;
    size_t dstoff = ((size_t)(row >> 4) * 2 + h) * 1024
                  + (size_t)(quad * 16 + (row & 15)) * 16 + p * 8 + (k & 7);
    *(unsigned int*)(dst + dstoff) = p32;

    #pragma unroll
    for (int m = 16; m; m >>= 1) s += __shfl_xor(s, m, 64);  // stays in 32-half
    if (k4 == 0) sq[row] = s;
}

// ---------------------------------------------------------------------------
// Main: EXACT R10 structure (51.4us, VGPR 64, 8 waves/SIMD — the compiler's
// sunk-load schedule + wave TLP is the winning regime; R11's sched_barrier
// experiment regressed 8x and is reverted). Only addition vs R10: finalize
// merged into the last block (replaces the separate 3rd launch).
// ---------------------------------------------------------------------------
__global__ __launch_bounds__(256, 4)
void chamfer_main(const unsigned char* __restrict__ xq, const unsigned char* __restrict__ yq,
                  const float* __restrict__ x2, const float* __restrict__ y2,
                  unsigned int* __restrict__ fwd, float* __restrict__ bpart,
                  unsigned int* __restrict__ counter, float* __restrict__ out) {
    __shared__ float x2s[BB][128];          // 4 KB
    __shared__ float y2s[BB][32];           // 1 KB
    __shared__ unsigned int fbuf[BB][32];   // 1 KB
    __shared__ float red[4], redb[4];
    __shared__ int isLast;

    const int tid  = threadIdx.x;
    const int lane = tid & 63;
    const int wave = tid >> 6;
    const int quad = lane >> 4;
    const int l15  = lane & 15;

    // 4096 blocks; per-XCD m-stripe: xcd = id&7 -> mb = xcd*16 + (j>>5)
    const int id  = blockIdx.x;
    const int xcd = id & 7;
    const int j   = id >> 3;                 // 0..511
    const int nb  = j & 31;                  // 0..31 (128 n each)
    const int mb  = xcd * 16 + (j >> 5);     // 0..127 (32 m each)
    const int n0b = nb * 128;
    const int n0w = n0b + wave * 32;
    const int m0  = mb * 32;

    const size_t lane16 = (size_t)lane * 16;
    const unsigned char* xbase = xq + (size_t)(n0w >> 4) * 2048 + lane16;
    const unsigned char* ybase = yq + (size_t)(m0 >> 4) * 2048 + lane16;

    // stage norms + init fbuf (once), then the only pre-loop barrier
    for (int i = tid; i < BB * 128; i += 256)
        x2s[i >> 7][i & 127] = x2[(size_t)(i >> 7) * NN + n0b + (i & 127)];
    if (tid < BB * 32) {
        y2s[tid >> 5][tid & 31] = y2[(size_t)(tid >> 5) * MM + m0 + (tid & 31)];
        ((unsigned int*)fbuf)[tid] = 0x7f800000u;
    }
    __syncthreads();

    long2v fx[2][2][2], fy[2][2][2];  // [buf][group][half]
    auto loadb = [&](int b, int s) {
        const unsigned char* xb = xbase + ((size_t)b << 19);  // b*256 groups*2KB
        const unsigned char* yb = ybase + ((size_t)b << 19);
        #pragma unroll
        for (int g2 = 0; g2 < 2; ++g2)
            #pragma unroll
            for (int h = 0; h < 2; ++h) {
                fx[s][g2][h] = *(const long2v*)(xb + ((g2 * 2 + h) << 10));
                fy[s][g2][h] = *(const long2v*)(yb + ((g2 * 2 + h) << 10));
            }
    };
    loadb(0, 0);

    const float INF = __builtin_inff();
    f32x4 bmin[2][2];
    #pragma unroll
    for (int fi = 0; fi < 2; ++fi)
        #pragma unroll
        for (int fj = 0; fj < 2; ++fj)
            bmin[fi][fj] = (f32x4){INF, INF, INF, INF};

    #pragma unroll 2
    for (int b = 0; b < BB; ++b) {
        const int cur = b & 1;
        if (b < BB - 1) loadb(b + 1, cur ^ 1);  // the ONLY vmem in the loop

        f32x4 acc[2][2];
        #pragma unroll
        for (int fi = 0; fi < 2; ++fi)
            #pragma unroll
            for (int fj = 0; fj < 2; ++fj)
                acc[fi][fj] = (f32x4){0.f, 0.f, 0.f, 0.f};

        #pragma unroll
        for (int h = 0; h < 2; ++h)
            #pragma unroll
            for (int p = 0; p < 2; ++p)
                #pragma unroll
                for (int fi = 0; fi < 2; ++fi)
                    #pragma unroll
                    for (int fj = 0; fj < 2; ++fj)
                        acc[fi][fj] = __builtin_amdgcn_mfma_f32_16x16x32_fp8_fp8(
                            fx[cur][fi][h][p], fy[cur][fj][h][p], acc[fi][fj], 0, 0, 0);

        // epilogue on SQUARED distances; norms from LDS; NO shfl, NO branch
        float y2v[2];
        y2v[0] = y2s[b][l15];
        y2v[1] = y2s[b][16 + l15];
        float fm[2] = {INF, INF};
        #pragma unroll
        for (int fi = 0; fi < 2; ++fi) {
            const f32x4 x2v = *(const f32x4*)&x2s[b][wave * 32 + fi * 16 + quad * 4];
            #pragma unroll
            for (int fj = 0; fj < 2; ++fj)
                #pragma unroll
                for (int e = 0; e < 4; ++e) {
                    float sqv = fmaf(-2.0f, acc[fi][fj][e], x2v[e] + y2v[fj]);
                    bmin[fi][fj][e] = fminf(bmin[fi][fj][e], sqv);
                    fm[fj]          = fminf(fm[fj], sqv);
                }
        }
        #pragma unroll
        for (int fj = 0; fj < 2; ++fj) {
            // 4 quads same address: no-return ds_min, pipelined, no chain
            atomicMin(&fbuf[b][fj * 16 + l15],
                      __float_as_uint(fmaxf(fm[fj], 0.0f)));
        }
    }
    __syncthreads();  // all waves' fbuf contributions visible

    // flush forward mins: 256 entries, one per thread
    {
        int b = tid >> 5, c = tid & 31;
        atomicMin(&fwd[(size_t)b * MM + m0 + c], fbuf[b][c]);
    }

    // backward: sqrt(clamp(min-over-b)), block-reduce, ONE plain store/block
    float s = 0.0f;
    #pragma unroll
    for (int fi = 0; fi < 2; ++fi)
        #pragma unroll
        for (int fj = 0; fj < 2; ++fj)
            #pragma unroll
            for (int e = 0; e < 4; ++e)
                s += sqrtf(fmaxf(bmin[fi][fj][e], 0.0f));
    #pragma unroll
    for (int off = 32; off; off >>= 1) s += __shfl_down(s, off, 64);
    if (lane == 0) red[wave] = s;
    __syncthreads();
    if (tid == 0) bpart[id] = red[0] + red[1] + red[2] + red[3];

    // merged finalize: last block reduces fwd (128 KB, L2-resident) + bpart
    __threadfence();
    __syncthreads();
    if (tid == 0) {
        unsigned int c = atomicAdd(counter, 1u);
        isLast = (c == (unsigned int)(gridDim.x - 1)) ? 1 : 0;
    }
    __syncthreads();
    if (isLast) {
        __threadfence();
        float sf = 0.0f, sb = 0.0f;
        const uint4* fw4 = (const uint4*)fwd;
        for (int i = tid; i < (BB * MM) / 4; i += 256) {
            uint4 u = fw4[i];
            sf += sqrtf(__uint_as_float(u.x)) + sqrtf(__uint_as_float(u.y)) +
                  sqrtf(__uint_as_float(u.z)) + sqrtf(__uint_as_float(u.w));
        }
        for (int i = tid; i < 4096; i += 256) sb += bpart[i];
        #pragma unroll
        for (int off = 32; off; off >>= 1) {
            sf += __shfl_down(sf, off, 64);
            sb += __shfl_down(sb, off, 64);
        }
        if (lane == 0) { red[wave] = sf; redb[wave] = sb; }
        __syncthreads();
        if (tid == 0) {
            float ftot = red[0] + red[1] + red[2] + red[3];
            float btot = redb[0] + redb[1] + redb[2] + redb[3];
            out[0] = ftot / (float)(BB * MM) + btot / ((float)NN * (float)MM);
        }
    }
}

extern "C" void kernel_launch(void* const* d_in, const int* in_sizes, int n_in,
                              void* d_out, int out_size, void* d_ws, size_t ws_size,
                              hipStream_t stream) {
    const float* x = (const float*)d_in[0];  // (B,N,D)
    const float* y = (const float*)d_in[1];  // (B,M,D)
    float* out = (float*)d_out;

    char* w = (char*)d_ws;
    unsigned char* xq = (unsigned char*)(w);               // 4 MB fp8 (frag order)
    unsigned char* yq = (unsigned char*)(w + 4194304);     // 4 MB fp8 (frag order)
    float*    x2 = (float*)(w + 8388608);                  // 128 KB
    float*    y2 = (float*)(w + 8519680);                  // 128 KB
    unsigned int* fwd = (unsigned int*)(w + 8650752);      // 128 KB
    float*    bpart = (float*)(w + 8781824);               // 16 KB
    unsigned int* counter = (unsigned int*)(w + 8798208);  // 4 B

    // 65536 rows, one per 32 lanes -> 2M threads
    prep_all<<<(2 * BB * NN * 32) / 256, 256, 0, stream>>>(x, y, xq, yq, x2, y2,
                                                           fwd, counter);
    chamfer_main<<<4096, 256, 0, stream>>>(xq, yq, x2, y2, fwd, bpart, counter, out);
}

// Round 13
// 123.717 us; speedup vs baseline: 3.7951x; 3.7602x over previous
//
#include <hip/hip_runtime.h>
#include <hip/hip_fp8.h>

#define BB 8
#define NN 4096
#define MM 4096
#define DD 128

typedef float f32x4 __attribute__((ext_vector_type(4)));
typedef long  long2v __attribute__((ext_vector_type(2)));

// ---------------------------------------------------------------------------
// Fragment-ordered fp8 layout (verified R7-R12, absmax 0): for 16-row group
// g, K-half h, the 1KB unit holds lane(quad,l15) -> 16B: row=l15 (in group),
// k=(2h+p)*32+quad*8+(0..7) at byte p*8+(k&7).
//
// LESSON (R11/R12): __threadfence() in every block = per-XCD L2 invalidate
// (buffer_inv sc0 sc1) -> 8x regression. Fences only in the tiny finalize
// kernel. Main kernel must stay fence-free.
// ---------------------------------------------------------------------------

// Prep: one row per 32 lanes, float4/thread, HW packed fp8 convert
// (v_cvt_pk_fp8_f32), exact fp32 norms via shfl, scattered 4B
// fragment-ordered stores. Also inits fwd/bsum/fsum/counter.
__global__ __launch_bounds__(256)
void prep_all(const float* __restrict__ x, const float* __restrict__ y,
              unsigned char* __restrict__ xq, unsigned char* __restrict__ yq,
              float* __restrict__ x2, float* __restrict__ y2,
              unsigned int* __restrict__ fwd, float* __restrict__ bsum,
              float* __restrict__ fsum, unsigned int* __restrict__ counter) {
    int gtid = blockIdx.x * blockDim.x + threadIdx.x;
    if (gtid < BB * MM) fwd[gtid] = 0x7f800000u;  // +inf bits
    if (gtid == 0) { *bsum = 0.0f; *fsum = 0.0f; *counter = 0u; }

    int row = gtid >> 5;
    int k4  = gtid & 31;
    const float* src;
    unsigned char* dst;
    float* sq;
    if (row < BB * NN) {
        src = x; dst = xq; sq = x2;
    } else {
        src = y; dst = yq; sq = y2; row -= BB * NN;
    }
    f32x4 v = ((const f32x4*)src)[(size_t)row * 32 + k4];
    float s = v.x * v.x + v.y * v.y + v.z * v.z + v.w * v.w;
    // bytes: [x][y][z][w] little-endian (verified, absmax 0 vs fp32 ref)
    unsigned int p32 = (unsigned int)__builtin_amdgcn_cvt_pk_fp8_f32(v.x, v.y, 0, false);
    p32 = (unsigned int)__builtin_amdgcn_cvt_pk_fp8_f32(v.z, v.w, (int)p32, true);

    int k    = k4 << 2;
    int kk   = k >> 5;
    int h    = kk >> 1;
    int p    = kk & 1;
    int quad = (k >> 3) & 3;
    size_t dstoff = ((size_t)(row >> 4) * 2 + h) * 1024
                  + (size_t)(quad * 16 + (row & 15)) * 16 + p * 8 + (k & 7);
    *(unsigned int*)(dst + dstoff) = p32;

    #pragma unroll
    for (int m = 16; m; m >>= 1) s += __shfl_xor(s, m, 64);  // stays in 32-half
    if (k4 == 0) sq[row] = s;
}

// ---------------------------------------------------------------------------
// Main: EXACT R10 structure (51.4us, VGPR 64, 8 waves/SIMD). Fence-free.
// Wave tile 32n x 32m, block 128n x 32m; only vmem in the loop is the b+1
// fragment prefetch (compiler sinks it — wave TLP does the hiding, proven
// better than every explicit pipelining attempt R3/R4/R8/R11).
// ---------------------------------------------------------------------------
__global__ __launch_bounds__(256, 4)
void chamfer_main(const unsigned char* __restrict__ xq, const unsigned char* __restrict__ yq,
                  const float* __restrict__ x2, const float* __restrict__ y2,
                  unsigned int* __restrict__ fwd, float* __restrict__ bpart) {
    __shared__ float x2s[BB][128];          // 4 KB
    __shared__ float y2s[BB][32];           // 1 KB
    __shared__ unsigned int fbuf[BB][32];   // 1 KB
    __shared__ float red[4];

    const int tid  = threadIdx.x;
    const int lane = tid & 63;
    const int wave = tid >> 6;
    const int quad = lane >> 4;
    const int l15  = lane & 15;

    // 4096 blocks; per-XCD m-stripe: xcd = id&7 -> mb = xcd*16 + (j>>5)
    const int id  = blockIdx.x;
    const int xcd = id & 7;
    const int j   = id >> 3;                 // 0..511
    const int nb  = j & 31;                  // 0..31 (128 n each)
    const int mb  = xcd * 16 + (j >> 5);     // 0..127 (32 m each)
    const int n0b = nb * 128;
    const int n0w = n0b + wave * 32;
    const int m0  = mb * 32;

    const size_t lane16 = (size_t)lane * 16;
    const unsigned char* xbase = xq + (size_t)(n0w >> 4) * 2048 + lane16;
    const unsigned char* ybase = yq + (size_t)(m0 >> 4) * 2048 + lane16;

    // stage norms + init fbuf (once), then the only pre-loop barrier
    for (int i = tid; i < BB * 128; i += 256)
        x2s[i >> 7][i & 127] = x2[(size_t)(i >> 7) * NN + n0b + (i & 127)];
    if (tid < BB * 32) {
        y2s[tid >> 5][tid & 31] = y2[(size_t)(tid >> 5) * MM + m0 + (tid & 31)];
        ((unsigned int*)fbuf)[tid] = 0x7f800000u;
    }
    __syncthreads();

    long2v fx[2][2][2], fy[2][2][2];  // [buf][group][half]
    auto loadb = [&](int b, int s) {
        const unsigned char* xb = xbase + ((size_t)b << 19);  // b*256 groups*2KB
        const unsigned char* yb = ybase + ((size_t)b << 19);
        #pragma unroll
        for (int g2 = 0; g2 < 2; ++g2)
            #pragma unroll
            for (int h = 0; h < 2; ++h) {
                fx[s][g2][h] = *(const long2v*)(xb + ((g2 * 2 + h) << 10));
                fy[s][g2][h] = *(const long2v*)(yb + ((g2 * 2 + h) << 10));
            }
    };
    loadb(0, 0);

    const float INF = __builtin_inff();
    f32x4 bmin[2][2];
    #pragma unroll
    for (int fi = 0; fi < 2; ++fi)
        #pragma unroll
        for (int fj = 0; fj < 2; ++fj)
            bmin[fi][fj] = (f32x4){INF, INF, INF, INF};

    #pragma unroll 2
    for (int b = 0; b < BB; ++b) {
        const int cur = b & 1;
        if (b < BB - 1) loadb(b + 1, cur ^ 1);  // the ONLY vmem in the loop

        f32x4 acc[2][2];
        #pragma unroll
        for (int fi = 0; fi < 2; ++fi)
            #pragma unroll
            for (int fj = 0; fj < 2; ++fj)
                acc[fi][fj] = (f32x4){0.f, 0.f, 0.f, 0.f};

        #pragma unroll
        for (int h = 0; h < 2; ++h)
            #pragma unroll
            for (int p = 0; p < 2; ++p)
                #pragma unroll
                for (int fi = 0; fi < 2; ++fi)
                    #pragma unroll
                    for (int fj = 0; fj < 2; ++fj)
                        acc[fi][fj] = __builtin_amdgcn_mfma_f32_16x16x32_fp8_fp8(
                            fx[cur][fi][h][p], fy[cur][fj][h][p], acc[fi][fj], 0, 0, 0);

        // epilogue on SQUARED distances; norms from LDS; NO shfl, NO branch
        float y2v[2];
        y2v[0] = y2s[b][l15];
        y2v[1] = y2s[b][16 + l15];
        float fm[2] = {INF, INF};
        #pragma unroll
        for (int fi = 0; fi < 2; ++fi) {
            const f32x4 x2v = *(const f32x4*)&x2s[b][wave * 32 + fi * 16 + quad * 4];
            #pragma unroll
            for (int fj = 0; fj < 2; ++fj)
                #pragma unroll
                for (int e = 0; e < 4; ++e) {
                    float sqv = fmaf(-2.0f, acc[fi][fj][e], x2v[e] + y2v[fj]);
                    bmin[fi][fj][e] = fminf(bmin[fi][fj][e], sqv);
                    fm[fj]          = fminf(fm[fj], sqv);
                }
        }
        #pragma unroll
        for (int fj = 0; fj < 2; ++fj) {
            // 4 quads same address: no-return ds_min, pipelined, no chain
            atomicMin(&fbuf[b][fj * 16 + l15],
                      __float_as_uint(fmaxf(fm[fj], 0.0f)));
        }
    }
    __syncthreads();  // all waves' fbuf contributions visible

    // flush forward mins: 256 entries, one per thread (device-scope atomic,
    // coherent at the L2 coherence point — no fence needed)
    {
        int b = tid >> 5, c = tid & 31;
        atomicMin(&fwd[(size_t)b * MM + m0 + c], fbuf[b][c]);
    }

    // backward: sqrt(clamp(min-over-b)), block-reduce, ONE plain store/block
    float s = 0.0f;
    #pragma unroll
    for (int fi = 0; fi < 2; ++fi)
        #pragma unroll
        for (int fj = 0; fj < 2; ++fj)
            #pragma unroll
            for (int e = 0; e < 4; ++e)
                s += sqrtf(fmaxf(bmin[fi][fj][e], 0.0f));
    #pragma unroll
    for (int off = 32; off; off >>= 1) s += __shfl_down(s, off, 64);
    if (lane == 0) red[wave] = s;
    __syncthreads();
    if (tid == 0) bpart[id] = red[0] + red[1] + red[2] + red[3];
}

// Finalize: 32 blocks x 256 threads. fwd: one uint4/thread; bpart: one/thread.
// The (cheap, 32x) device fences live HERE, not in the 4096-block main.
__global__ __launch_bounds__(256)
void finalize_kernel(const unsigned int* __restrict__ fwd,
                     const float* __restrict__ bpart,
                     float* __restrict__ bsum, float* __restrict__ fsum,
                     unsigned int* __restrict__ counter, float* __restrict__ out) {
    __shared__ float redf[4], redb[4];
    __shared__ int isLast;
    const int tid = threadIdx.x, lane = tid & 63, wave = tid >> 6;
    const int gtid = blockIdx.x * 256 + tid;
    uint4 u = ((const uint4*)fwd)[gtid];
    float sf = sqrtf(__uint_as_float(u.x)) + sqrtf(__uint_as_float(u.y)) +
               sqrtf(__uint_as_float(u.z)) + sqrtf(__uint_as_float(u.w));
    float sb = (gtid < 4096) ? bpart[gtid] : 0.0f;
    #pragma unroll
    for (int off = 32; off; off >>= 1) {
        sf += __shfl_down(sf, off, 64);
        sb += __shfl_down(sb, off, 64);
    }
    if (lane == 0) { redf[wave] = sf; redb[wave] = sb; }
    __syncthreads();
    if (tid == 0) {
        atomicAdd(fsum, redf[0] + redf[1] + redf[2] + redf[3]);
        atomicAdd(bsum, redb[0] + redb[1] + redb[2] + redb[3]);
        __threadfence();
        unsigned int c = atomicAdd(counter, 1u);
        isLast = (c == gridDim.x - 1) ? 1 : 0;
        if (isLast) {
            __threadfence();
            float fs = __hip_atomic_load(fsum, __ATOMIC_RELAXED,
                                         __HIP_MEMORY_SCOPE_AGENT);
            float bs = __hip_atomic_load(bsum, __ATOMIC_RELAXED,
                                         __HIP_MEMORY_SCOPE_AGENT);
            out[0] = fs / (float)(BB * MM) + bs / ((float)NN * (float)MM);
        }
    }
}

extern "C" void kernel_launch(void* const* d_in, const int* in_sizes, int n_in,
                              void* d_out, int out_size, void* d_ws, size_t ws_size,
                              hipStream_t stream) {
    const float* x = (const float*)d_in[0];  // (B,N,D)
    const float* y = (const float*)d_in[1];  // (B,M,D)
    float* out = (float*)d_out;

    char* w = (char*)d_ws;
    unsigned char* xq = (unsigned char*)(w);               // 4 MB fp8 (frag order)
    unsigned char* yq = (unsigned char*)(w + 4194304);     // 4 MB fp8 (frag order)
    float*    x2 = (float*)(w + 8388608);                  // 128 KB
    float*    y2 = (float*)(w + 8519680);                  // 128 KB
    unsigned int* fwd = (unsigned int*)(w + 8650752);      // 128 KB
    float*    bpart = (float*)(w + 8781824);               // 16 KB
    float*    bsum = (float*)(w + 8798208);                // 4 B
    float*    fsum = (float*)(w + 8798212);                // 4 B
    unsigned int* counter = (unsigned int*)(w + 8798216);  // 4 B

    // 65536 rows, one per 32 lanes -> 2M threads
    prep_all<<<(2 * BB * NN * 32) / 256, 256, 0, stream>>>(x, y, xq, yq, x2, y2,
                                                           fwd, bsum, fsum, counter);
    chamfer_main<<<4096, 256, 0, stream>>>(xq, yq, x2, y2, fwd, bpart);
    finalize_kernel<<<32, 256, 0, stream>>>(fwd, bpart, bsum, fsum, counter, out);
}